// Round 3
// baseline (1818.662 us; speedup 1.0000x reference)
//
#include <hip/hip_runtime.h>
#include <stdint.h>

#define Bn 32
#define Nn 256
#define En 512
#define Hn 8
#define Dn 64

// ---- bf16 helpers (workspace fallback only) --------------------------------
__device__ __forceinline__ float bfld(const unsigned short* p){ union{uint32_t i; float f;} v; v.i = ((uint32_t)(*p))<<16; return v.f; }
__device__ __forceinline__ unsigned short f2bf(float f){
  union{float f; uint32_t i;} v; v.f = f;
  uint32_t i = v.i;
  uint32_t r = (i + 0x7fffu + ((i>>16)&1u)) >> 16;   // round-to-nearest-even
  return (unsigned short)r;
}
// workspace store/load, wsf=1 -> fp32 workspace, wsf=0 -> bf16 workspace
__device__ __forceinline__ void wst(void* ws, size_t idx, float v, int wsf){
  if (wsf) ((float*)ws)[idx] = v; else ((unsigned short*)ws)[idx] = f2bf(v);
}
__device__ __forceinline__ float wld(const void* ws, size_t idx, int wsf){
  if (wsf) return ((const float*)ws)[idx];
  return bfld((const unsigned short*)ws + idx);
}

// ---------------------------------------------------------------------------
// Kernel A: qkv = x @ w_qkv^T + b_qkv -> q/k/v workspace [B,H,N,D].
// Grid: 2048 row-tiles x 6 col-tiles, 256 threads.
// ---------------------------------------------------------------------------
__global__ __launch_bounds__(256) void qkv_kernel(
    const float* __restrict__ x, const float* __restrict__ wq,
    const float* __restrict__ bq,
    void* __restrict__ q_ws, void* __restrict__ k_ws, void* __restrict__ v_ws,
    int wsf){
  __shared__ float s_x[4][512];
  int bid = blockIdx.x, tid = threadIdx.x;
  int rt = bid / 6, ct = bid % 6;
  int row0 = rt * 4;
  // stage 4 x-rows: thread tid loads row tid>>6, cols (tid&63)*8 .. +7
  {
    int r = tid >> 6, c8 = (tid & 63) * 8;
    const float4* xp = reinterpret_cast<const float4*>(x + (size_t)(row0 + r) * 512 + c8);
    float4 a = xp[0], b = xp[1];
    float* dst = &s_x[r][c8];
    dst[0]=a.x; dst[1]=a.y; dst[2]=a.z; dst[3]=a.w;
    dst[4]=b.x; dst[5]=b.y; dst[6]=b.z; dst[7]=b.w;
  }
  __syncthreads();
  int c = ct * 256 + tid;                     // output channel 0..1535
  const float4* wp = reinterpret_cast<const float4*>(wq + (size_t)c * 512);
  float acc0=0.f, acc1=0.f, acc2=0.f, acc3=0.f;
  for (int kk = 0; kk < 128; ++kk) {          // 128 x float4 = 512 floats
    float4 w = wp[kk];
    const float* x0 = &s_x[0][kk*4];
    const float* x1 = &s_x[1][kk*4];
    const float* x2 = &s_x[2][kk*4];
    const float* x3 = &s_x[3][kk*4];
    acc0 += w.x*x0[0] + w.y*x0[1] + w.z*x0[2] + w.w*x0[3];
    acc1 += w.x*x1[0] + w.y*x1[1] + w.z*x1[2] + w.w*x1[3];
    acc2 += w.x*x2[0] + w.y*x2[1] + w.z*x2[2] + w.w*x2[3];
    acc3 += w.x*x3[0] + w.y*x3[1] + w.z*x3[2] + w.w*x3[3];
  }
  float bias = bq[c];
  int sec = c >> 9, ch = c & 511, h = ch >> 6, d = ch & 63;
  void* dst = (sec == 0) ? q_ws : ((sec == 1) ? k_ws : v_ws);
  float accs[4] = {acc0, acc1, acc2, acc3};
  #pragma unroll
  for (int rr = 0; rr < 4; ++rr) {
    int rowr = row0 + rr;
    int b = rowr >> 8, n = rowr & 255;
    wst(dst, (((size_t)b * Hn + h) * Nn + n) * Dn + d, accs[rr] + bias, wsf);
  }
}

// ---------------------------------------------------------------------------
// Kernel B: attention with additive bias from U @ w_u^T + b_u.
// One block per (b, query); thread m owns key m; LDS-tree softmax.
// ---------------------------------------------------------------------------
__global__ __launch_bounds__(256) void attn_kernel(
    const float* __restrict__ U, const float* __restrict__ w_u,
    const float* __restrict__ b_u,
    const void* __restrict__ q_ws, const void* __restrict__ k_ws,
    const void* __restrict__ v_ws, void* __restrict__ o_ws, int wsf){
  __shared__ float s_q[64];
  __shared__ float s_attn[256];
  __shared__ float s_red[256];
  __shared__ float s_wu[64];
  __shared__ float s_bu[8];
  int tid = threadIdx.x;
  int bq = blockIdx.x;               // b*N + qi
  int b = bq >> 8, qi = bq & 255;
  if (tid < 64) s_wu[tid] = w_u[tid];
  if (tid < 8)  s_bu[tid] = b_u[tid];
  int m = tid;
  float ur[8];
  {
    const float4* up = reinterpret_cast<const float4*>(U + ((size_t)bq * 256 + m) * 8);
    float4 a = up[0], c = up[1];
    ur[0]=a.x; ur[1]=a.y; ur[2]=a.z; ur[3]=a.w; ur[4]=c.x; ur[5]=c.y; ur[6]=c.z; ur[7]=c.w;
  }
  int d = tid & 63, g = tid >> 6;
  for (int h = 0; h < Hn; ++h) {
    __syncthreads();
    if (tid < 64) s_q[tid] = wld(q_ws, (((size_t)b * Hn + h) * Nn + qi) * Dn + tid, wsf);
    __syncthreads();
    // logit[m] = (q . k_m) * D^-0.5 + bias[h,m]
    size_t kbase = (((size_t)b * Hn + h) * Nn + m) * Dn;
    float dot = 0.f;
    if (wsf) {
      const float4* kp = reinterpret_cast<const float4*>((const float*)k_ws + kbase);
      #pragma unroll 16
      for (int kk = 0; kk < 16; ++kk) {
        float4 kv = kp[kk];
        const float* qs = s_q + kk * 4;
        dot += kv.x*qs[0] + kv.y*qs[1] + kv.z*qs[2] + kv.w*qs[3];
      }
    } else {
      const unsigned short* kp = (const unsigned short*)k_ws + kbase;
      #pragma unroll 8
      for (int kk = 0; kk < 64; ++kk) dot += bfld(kp + kk) * s_q[kk];
    }
    float bias = s_bu[h];
    #pragma unroll
    for (int i = 0; i < 8; ++i) bias += ur[i] * s_wu[h * 8 + i];
    float logit = dot * 0.125f + bias;
    // block max (LDS tree)
    s_red[tid] = logit; __syncthreads();
    for (int s = 128; s >= 1; s >>= 1) {
      if (tid < s) s_red[tid] = fmaxf(s_red[tid], s_red[tid + s]);
      __syncthreads();
    }
    float mmax = s_red[0]; __syncthreads();
    float e = __expf(logit - mmax);
    s_attn[tid] = e;
    // block sum (LDS tree)
    s_red[tid] = e; __syncthreads();
    for (int s = 128; s >= 1; s >>= 1) {
      if (tid < s) s_red[tid] += s_red[tid + s];
      __syncthreads();
    }
    float inv = 1.0f / s_red[0]; __syncthreads();
    // PV: thread (d, g) accumulates keys g*64..g*64+63 for output dim d
    size_t vbase = (((size_t)b * Hn + h) * Nn + g * 64) * Dn + d;
    float partial = 0.f;
    if (wsf) {
      const float* vb = (const float*)v_ws + vbase;
      #pragma unroll 8
      for (int mm = 0; mm < 64; ++mm) partial += s_attn[g * 64 + mm] * vb[(size_t)mm * 64];
    } else {
      const unsigned short* vb = (const unsigned short*)v_ws + vbase;
      #pragma unroll 8
      for (int mm = 0; mm < 64; ++mm) partial += s_attn[g * 64 + mm] * bfld(vb + (size_t)mm * 64);
    }
    s_red[tid] = partial; __syncthreads();
    if (tid < 64) {
      float o = (s_red[tid] + s_red[tid + 64] + s_red[tid + 128] + s_red[tid + 192]) * inv;
      wst(o_ws, (size_t)bq * 512 + h * 64 + tid, o, wsf);
    }
  }
}

// ---------------------------------------------------------------------------
// Kernel C: out = o @ w_out^T + b_out, fp32 store to d_out.
// ---------------------------------------------------------------------------
__global__ __launch_bounds__(256) void oproj_kernel(
    const void* __restrict__ o_ws, const float* __restrict__ w_out,
    const float* __restrict__ b_out, float* __restrict__ out, int wsf){
  __shared__ float s_o[4][512];
  int bid = blockIdx.x, tid = threadIdx.x;
  int rt = bid >> 1, t2 = bid & 1;
  int row0 = rt * 4;
  {
    int r = tid >> 6, c8 = (tid & 63) * 8;
    #pragma unroll
    for (int j = 0; j < 8; ++j)
      s_o[r][c8 + j] = wld(o_ws, (size_t)(row0 + r) * 512 + c8 + j, wsf);
  }
  __syncthreads();
  int e = t2 * 256 + tid;
  const float4* wp = reinterpret_cast<const float4*>(w_out + (size_t)e * 512);
  float acc0=0.f, acc1=0.f, acc2=0.f, acc3=0.f;
  for (int kk = 0; kk < 128; ++kk) {
    float4 w = wp[kk];
    const float* o0 = &s_o[0][kk*4];
    const float* o1 = &s_o[1][kk*4];
    const float* o2 = &s_o[2][kk*4];
    const float* o3 = &s_o[3][kk*4];
    acc0 += w.x*o0[0] + w.y*o0[1] + w.z*o0[2] + w.w*o0[3];
    acc1 += w.x*o1[0] + w.y*o1[1] + w.z*o1[2] + w.w*o1[3];
    acc2 += w.x*o2[0] + w.y*o2[1] + w.z*o2[2] + w.w*o2[3];
    acc3 += w.x*o3[0] + w.y*o3[1] + w.z*o3[2] + w.w*o3[3];
  }
  float bias = b_out[e];
  out[(size_t)(row0+0)*512 + e] = acc0 + bias;
  out[(size_t)(row0+1)*512 + e] = acc1 + bias;
  out[(size_t)(row0+2)*512 + e] = acc2 + bias;
  out[(size_t)(row0+3)*512 + e] = acc3 + bias;
}

extern "C" void kernel_launch(void* const* d_in, const int* in_sizes, int n_in,
                              void* d_out, int out_size, void* d_ws, size_t ws_size,
                              hipStream_t stream) {
  const float* x     = (const float*)d_in[0];
  const float* U     = (const float*)d_in[1];
  const float* w_qkv = (const float*)d_in[2];
  const float* b_qkv = (const float*)d_in[3];
  const float* w_out = (const float*)d_in[4];
  const float* b_out = (const float*)d_in[5];
  const float* w_u   = (const float*)d_in[6];
  const float* b_u   = (const float*)d_in[7];
  float* out = (float*)d_out;

  const size_t per = (size_t)Bn * Hn * Nn * Dn;  // 4,194,304 elements per array
  // Prefer fp32 workspace (4 arrays x 16.78 MB = 67.1 MB); fall back to bf16
  // (33.6 MB) if d_ws is too small. Decided host-side: constant across replays.
  int wsf = (ws_size >= per * 4 * sizeof(float)) ? 1 : 0;
  size_t esz = wsf ? sizeof(float) : sizeof(unsigned short);
  char* wsb = (char*)d_ws;
  void* q_ws = wsb;
  void* k_ws = wsb + per * esz;
  void* v_ws = wsb + 2 * per * esz;
  void* o_ws = wsb + 3 * per * esz;

  qkv_kernel<<<dim3((Bn*Nn/4) * 6), dim3(256), 0, stream>>>(x, w_qkv, b_qkv, q_ws, k_ws, v_ws, wsf);
  attn_kernel<<<dim3(Bn*Nn), dim3(256), 0, stream>>>(U, w_u, b_u, q_ws, k_ws, v_ws, o_ws, wsf);
  oproj_kernel<<<dim3((Bn*Nn/4) * 2), dim3(256), 0, stream>>>(o_ws, w_out, b_out, out, wsf);
}

// Round 4
// 365.066 us; speedup vs baseline: 4.9817x; 4.9817x over previous
//
#include <hip/hip_runtime.h>
#include <stdint.h>

#define Bn 32
#define Nn 256
#define En 512
#define Hn 8
#define Dn 64

typedef __attribute__((ext_vector_type(8))) short bf16x8;   // MFMA A/B frag (4 VGPRs)
typedef __attribute__((ext_vector_type(4))) short bf16x4;
typedef __attribute__((ext_vector_type(4))) float f32x4;    // MFMA C/D frag

__device__ __forceinline__ unsigned short f2bf(float f){
  union{float f; uint32_t i;} v; v.f = f;
  uint32_t i = v.i;
  return (unsigned short)((i + 0x7fffu + ((i>>16)&1u)) >> 16);  // RNE
}

// ---------------------------------------------------------------------------
// Kernel A: qkv = x @ w_qkv^T + b_qkv  (M=8192, N=1536, K=512), bf16 MFMA.
// q (pre-scaled by 1/8) and k -> [B,H,N,D]; v -> transposed [B,H,D,N].
// Block 256 thr, C-tile 128x128, waves 2x2 of 64x64, K-chunks of 32.
// ---------------------------------------------------------------------------
__global__ __launch_bounds__(256) void qkv_gemm(
    const float* __restrict__ x, const float* __restrict__ wq, const float* __restrict__ bq,
    unsigned short* __restrict__ q_ws, unsigned short* __restrict__ k_ws,
    unsigned short* __restrict__ v_ws){
  __shared__ unsigned short s_a[128][40];   // +8 pad: 2-way bank alias only
  __shared__ unsigned short s_b[128][40];
  const int tid = threadIdx.x;
  const int bx = blockIdx.x;            // col tile 0..11
  const int by = blockIdx.y;            // row tile 0..63
  const int row0 = by * 128, n0 = bx * 128;
  const int lane = tid & 63, wv = tid >> 6;
  const int wr = wv >> 1, wc = wv & 1;
  const int lm = lane & 15, quad = lane >> 4;
  const int sr = tid >> 3, sc4 = (tid & 7) * 4;   // staging row / col4
  f32x4 acc[4][4] = {};
  for (int kc = 0; kc < 16; ++kc) {
    const int k0 = kc * 32;
    __syncthreads();
    #pragma unroll
    for (int i = 0; i < 4; ++i) {
      int r = sr + i * 32;
      float4 va = *(const float4*)(x  + (size_t)(row0 + r) * 512 + k0 + sc4);
      float4 vb = *(const float4*)(wq + (size_t)(n0  + r) * 512 + k0 + sc4);
      bf16x4 pa, pb;
      pa[0]=(short)f2bf(va.x); pa[1]=(short)f2bf(va.y); pa[2]=(short)f2bf(va.z); pa[3]=(short)f2bf(va.w);
      pb[0]=(short)f2bf(vb.x); pb[1]=(short)f2bf(vb.y); pb[2]=(short)f2bf(vb.z); pb[3]=(short)f2bf(vb.w);
      *(bf16x4*)&s_a[r][sc4] = pa;
      *(bf16x4*)&s_b[r][sc4] = pb;
    }
    __syncthreads();
    bf16x8 af[4], bfr[4];
    #pragma unroll
    for (int mt = 0; mt < 4; ++mt) af[mt]  = *(const bf16x8*)&s_a[wr*64 + mt*16 + lm][quad*8];
    #pragma unroll
    for (int nt = 0; nt < 4; ++nt) bfr[nt] = *(const bf16x8*)&s_b[wc*64 + nt*16 + lm][quad*8];
    #pragma unroll
    for (int mt = 0; mt < 4; ++mt)
      #pragma unroll
      for (int nt = 0; nt < 4; ++nt)
        acc[mt][nt] = __builtin_amdgcn_mfma_f32_16x16x32_bf16(af[mt], bfr[nt], acc[mt][nt], 0, 0, 0);
  }
  #pragma unroll
  for (int nt = 0; nt < 4; ++nt) {
    int c = n0 + wc*64 + nt*16 + lm;    // output channel 0..1535
    float bias = bq[c];
    int sec = c >> 9, ch = c & 511, h = ch >> 6, d = ch & 63;
    #pragma unroll
    for (int mt = 0; mt < 4; ++mt) {
      #pragma unroll
      for (int r = 0; r < 4; ++r) {
        int grow = row0 + wr*64 + mt*16 + quad*4 + r;   // C/D: row=quad*4+reg, col=lane&15
        int b = grow >> 8, n = grow & 255;
        float val = acc[mt][nt][r] + bias;
        if (sec == 0)      q_ws[(((size_t)b*Hn + h)*Nn + n)*Dn + d] = f2bf(val * 0.125f);
        else if (sec == 1) k_ws[(((size_t)b*Hn + h)*Nn + n)*Dn + d] = f2bf(val);
        else               v_ws[(((size_t)b*Hn + h)*Dn + d)*Nn + n] = f2bf(val);
      }
    }
  }
}

// ---------------------------------------------------------------------------
// Kernel B: attention. Block = (b, 16-row q-tile); 4 waves x 2 heads = all 8
// heads -> U read exactly once per block. Bias built into MFMA C-accumulator.
// No __syncthreads in the hot loop; per-wave LDS strip for P layout change.
// ---------------------------------------------------------------------------
__global__ __launch_bounds__(256) void attn_kernel(
    const float* __restrict__ U, const float* __restrict__ w_u, const float* __restrict__ b_u,
    const unsigned short* __restrict__ q_ws, const unsigned short* __restrict__ k_ws,
    const unsigned short* __restrict__ v_ws, unsigned short* __restrict__ o_ws){
  __shared__ unsigned short s_p[4][16][264];   // per-wave P strip, +8 pad
  __shared__ float s_wu[64];
  __shared__ float s_bu[8];
  const int tid = threadIdx.x;
  const int wv = tid >> 6, lane = tid & 63;
  const int lm = lane & 15, quad = lane >> 4;
  const int blk = blockIdx.x;
  const int b = blk >> 4, qt0 = (blk & 15) * 16;
  if (tid < 64) s_wu[tid] = w_u[tid];
  if (tid < 8)  s_bu[tid] = b_u[tid];
  __syncthreads();   // only barrier in the kernel
  for (int hh = 0; hh < 2; ++hh) {
    const int h = wv * 2 + hh;
    const size_t hb = (size_t)b * Hn + h;
    f32x4 acc[16];
    // --- bias init: acc[kt][r] = U[b, qi, m, :] . w_u[h,:] + b_u[h]
    #pragma unroll
    for (int kt = 0; kt < 16; ++kt) {
      #pragma unroll
      for (int r = 0; r < 4; ++r) {
        const float4* up = (const float4*)(U +
            (((size_t)(b*Nn + qt0 + quad*4 + r))*Nn + kt*16 + lm)*8);
        float4 u0 = up[0], u1 = up[1];
        float s = s_bu[h];
        s += u0.x*s_wu[h*8+0] + u0.y*s_wu[h*8+1] + u0.z*s_wu[h*8+2] + u0.w*s_wu[h*8+3];
        s += u1.x*s_wu[h*8+4] + u1.y*s_wu[h*8+5] + u1.z*s_wu[h*8+6] + u1.w*s_wu[h*8+7];
        acc[kt][r] = s;
      }
    }
    // --- QK^T (q pre-scaled by 1/8 in qkv_gemm); A row = q row, B row = k row
    const unsigned short* qrow = q_ws + (hb*Nn + qt0 + lm)*Dn;
    bf16x8 a0 = *(const bf16x8*)(qrow + quad*8);
    bf16x8 a1 = *(const bf16x8*)(qrow + 32 + quad*8);
    for (int kt = 0; kt < 16; ++kt) {
      const unsigned short* krow = k_ws + (hb*Nn + kt*16 + lm)*Dn;
      bf16x8 b0 = *(const bf16x8*)(krow + quad*8);
      bf16x8 b1 = *(const bf16x8*)(krow + 32 + quad*8);
      acc[kt] = __builtin_amdgcn_mfma_f32_16x16x32_bf16(a0, b0, acc[kt], 0, 0, 0);
      acc[kt] = __builtin_amdgcn_mfma_f32_16x16x32_bf16(a1, b1, acc[kt], 0, 0, 0);
    }
    // --- softmax: row (quad*4+r) spans 16 kt in-lane x 16 lanes of this quad
    float mx[4], sm[4], inv[4];
    #pragma unroll
    for (int r = 0; r < 4; ++r) {
      float m = acc[0][r];
      #pragma unroll
      for (int kt = 1; kt < 16; ++kt) m = fmaxf(m, acc[kt][r]);
      #pragma unroll
      for (int msk = 1; msk < 16; msk <<= 1) m = fmaxf(m, __shfl_xor(m, msk));
      mx[r] = m; sm[r] = 0.f;
    }
    #pragma unroll
    for (int kt = 0; kt < 16; ++kt)
      #pragma unroll
      for (int r = 0; r < 4; ++r) {
        float e = __expf(acc[kt][r] - mx[r]);
        acc[kt][r] = e; sm[r] += e;
      }
    #pragma unroll
    for (int r = 0; r < 4; ++r) {
      float s = sm[r];
      #pragma unroll
      for (int msk = 1; msk < 16; msk <<= 1) s += __shfl_xor(s, msk);
      inv[r] = 1.0f / s;
    }
    // --- P (unnormalized, bf16) C-layout -> LDS strip
    #pragma unroll
    for (int kt = 0; kt < 16; ++kt)
      #pragma unroll
      for (int r = 0; r < 4; ++r)
        s_p[wv][quad*4 + r][kt*16 + lm] = f2bf(acc[kt][r]);
    // --- PV: A from s_p (A-layout reads), B from transposed V in global (L2-hot)
    f32x4 o[4] = {};
    #pragma unroll
    for (int ks = 0; ks < 8; ++ks) {
      bf16x8 ap = *(const bf16x8*)&s_p[wv][lm][ks*32 + quad*8];
      #pragma unroll
      for (int nt = 0; nt < 4; ++nt) {
        bf16x8 bv = *(const bf16x8*)(v_ws + (hb*Dn + nt*16 + lm)*Nn + ks*32 + quad*8);
        o[nt] = __builtin_amdgcn_mfma_f32_16x16x32_bf16(ap, bv, o[nt], 0, 0, 0);
      }
    }
    // --- normalize + store O -> o_ws[B,N,E] (channel = h*64+d)
    #pragma unroll
    for (int nt = 0; nt < 4; ++nt)
      #pragma unroll
      for (int r = 0; r < 4; ++r) {
        int n = qt0 + quad*4 + r;
        o_ws[((size_t)(b*Nn + n))*En + h*Dn + nt*16 + lm] = f2bf(o[nt][r] * inv[r]);
      }
  }
}

// ---------------------------------------------------------------------------
// Kernel C: out = o @ w_out^T + b_out (M=8192, N=512, K=512), fp32 out.
// ---------------------------------------------------------------------------
__global__ __launch_bounds__(256) void oproj_gemm(
    const unsigned short* __restrict__ o_ws, const float* __restrict__ wo,
    const float* __restrict__ bo, float* __restrict__ out){
  __shared__ unsigned short s_a[128][40];
  __shared__ unsigned short s_b[128][40];
  const int tid = threadIdx.x;
  const int bx = blockIdx.x;            // 0..3
  const int by = blockIdx.y;            // 0..63
  const int row0 = by * 128, n0 = bx * 128;
  const int lane = tid & 63, wv = tid >> 6;
  const int wr = wv >> 1, wc = wv & 1;
  const int lm = lane & 15, quad = lane >> 4;
  const int sr = tid >> 3, sc4 = (tid & 7) * 4;
  f32x4 acc[4][4] = {};
  for (int kc = 0; kc < 16; ++kc) {
    const int k0 = kc * 32;
    __syncthreads();
    // A: already bf16 in o_ws -> direct 16B copies
    #pragma unroll
    for (int i = 0; i < 2; ++i) {
      int g = tid * 2 + i;
      int r = g >> 2, c8 = (g & 3) * 8;
      *(bf16x8*)&s_a[r][c8] = *(const bf16x8*)(o_ws + (size_t)(row0 + r)*512 + k0 + c8);
    }
    // B: w_out fp32 -> bf16
    #pragma unroll
    for (int i = 0; i < 4; ++i) {
      int r = sr + i * 32;
      float4 vb = *(const float4*)(wo + (size_t)(n0 + r) * 512 + k0 + sc4);
      bf16x4 pb;
      pb[0]=(short)f2bf(vb.x); pb[1]=(short)f2bf(vb.y); pb[2]=(short)f2bf(vb.z); pb[3]=(short)f2bf(vb.w);
      *(bf16x4*)&s_b[r][sc4] = pb;
    }
    __syncthreads();
    bf16x8 af[4], bfr[4];
    #pragma unroll
    for (int mt = 0; mt < 4; ++mt) af[mt]  = *(const bf16x8*)&s_a[wr*64 + mt*16 + lm][quad*8];
    #pragma unroll
    for (int nt = 0; nt < 4; ++nt) bfr[nt] = *(const bf16x8*)&s_b[wc*64 + nt*16 + lm][quad*8];
    #pragma unroll
    for (int mt = 0; mt < 4; ++mt)
      #pragma unroll
      for (int nt = 0; nt < 4; ++nt)
        acc[mt][nt] = __builtin_amdgcn_mfma_f32_16x16x32_bf16(af[mt], bfr[nt], acc[mt][nt], 0, 0, 0);
  }
  #pragma unroll
  for (int nt = 0; nt < 4; ++nt) {
    int c = n0 + wc*64 + nt*16 + lm;
    float bias = bo[c];
    #pragma unroll
    for (int mt = 0; mt < 4; ++mt)
      #pragma unroll
      for (int r = 0; r < 4; ++r) {
        int grow = row0 + wr*64 + mt*16 + quad*4 + r;
        out[(size_t)grow*512 + c] = acc[mt][nt][r] + bias;
      }
  }
}

extern "C" void kernel_launch(void* const* d_in, const int* in_sizes, int n_in,
                              void* d_out, int out_size, void* d_ws, size_t ws_size,
                              hipStream_t stream) {
  const float* x     = (const float*)d_in[0];
  const float* U     = (const float*)d_in[1];
  const float* w_qkv = (const float*)d_in[2];
  const float* b_qkv = (const float*)d_in[3];
  const float* w_out = (const float*)d_in[4];
  const float* b_out = (const float*)d_in[5];
  const float* w_u   = (const float*)d_in[6];
  const float* b_u   = (const float*)d_in[7];
  float* out = (float*)d_out;

  const size_t per = (size_t)Bn * Hn * Nn * Dn;       // 4,194,304 elements
  unsigned short* q_ws = (unsigned short*)d_ws;       // total ws: 4 x 8 MiB = 32 MiB (proven fits)
  unsigned short* k_ws = q_ws + per;
  unsigned short* v_ws = k_ws + per;                  // transposed [B,H,D,N]
  unsigned short* o_ws = v_ws + per;                  // [B,N,E]

  qkv_gemm  <<<dim3(12, 64), dim3(256), 0, stream>>>(x, w_qkv, b_qkv, q_ws, k_ws, v_ws);
  attn_kernel<<<dim3(Bn * 16), dim3(256), 0, stream>>>(U, w_u, b_u, q_ws, k_ws, v_ws, o_ws);
  oproj_gemm<<<dim3(4, 64), dim3(256), 0, stream>>>(o_ws, w_out, b_out, out);
}

// Round 5
// 341.269 us; speedup vs baseline: 5.3291x; 1.0697x over previous
//
#include <hip/hip_runtime.h>
#include <stdint.h>

#define Bn 32
#define Nn 256
#define En 512
#define Hn 8
#define Dn 64

typedef __attribute__((ext_vector_type(8))) short bf16x8;   // MFMA A/B frag (4 VGPRs)
typedef __attribute__((ext_vector_type(4))) short bf16x4;
typedef __attribute__((ext_vector_type(4))) float f32x4;    // MFMA C/D frag

__device__ __forceinline__ unsigned short f2bf(float f){
  union{float f; uint32_t i;} v; v.f = f;
  uint32_t i = v.i;
  return (unsigned short)((i + 0x7fffu + ((i>>16)&1u)) >> 16);  // RNE
}

// ---------------------------------------------------------------------------
// Kernel 0: x fp32 -> bf16 into spare workspace (o_ws region, exactly x-sized).
// ---------------------------------------------------------------------------
__global__ __launch_bounds__(256) void convert_x(
    const float* __restrict__ x, unsigned short* __restrict__ xb){
  size_t i = ((size_t)blockIdx.x * 256 + threadIdx.x) * 8;
  float4 a = *(const float4*)(x + i);
  float4 b = *(const float4*)(x + i + 4);
  bf16x8 p;
  p[0]=(short)f2bf(a.x); p[1]=(short)f2bf(a.y); p[2]=(short)f2bf(a.z); p[3]=(short)f2bf(a.w);
  p[4]=(short)f2bf(b.x); p[5]=(short)f2bf(b.y); p[6]=(short)f2bf(b.z); p[7]=(short)f2bf(b.w);
  *(bf16x8*)(xb + i) = p;
}

// ---------------------------------------------------------------------------
// Kernel A: qkv = x @ w_qkv^T + b_qkv  (M=8192, N=1536, K=512), bf16 MFMA.
// A (x) pre-converted bf16 -> pure 16B copies into LDS. B converts fp32->bf16.
// q (pre-scaled by 1/8), k -> [B,H,N,D]; v -> transposed [B,H,D,N].
// ---------------------------------------------------------------------------
__global__ __launch_bounds__(256) void qkv_gemm(
    const unsigned short* __restrict__ xb, const float* __restrict__ wq,
    const float* __restrict__ bq,
    unsigned short* __restrict__ q_ws, unsigned short* __restrict__ k_ws,
    unsigned short* __restrict__ v_ws){
  __shared__ unsigned short s_a[128][40];   // +8 pad
  __shared__ unsigned short s_b[128][40];
  const int tid = threadIdx.x;
  const int bx = blockIdx.x;            // col tile 0..11
  const int by = blockIdx.y;            // row tile 0..63
  const int row0 = by * 128, n0 = bx * 128;
  const int lane = tid & 63, wv = tid >> 6;
  const int wr = wv >> 1, wc = wv & 1;
  const int lm = lane & 15, quad = lane >> 4;
  const int sr = tid >> 3, sc4 = (tid & 7) * 4;
  f32x4 acc[4][4] = {};
  for (int kc = 0; kc < 16; ++kc) {
    const int k0 = kc * 32;
    __syncthreads();
    #pragma unroll
    for (int i = 0; i < 2; ++i) {        // A: direct bf16 16B copies
      int g = tid * 2 + i;
      int r = g >> 2, c8 = (g & 3) * 8;
      *(bf16x8*)&s_a[r][c8] = *(const bf16x8*)(xb + (size_t)(row0 + r)*512 + k0 + c8);
    }
    #pragma unroll
    for (int i = 0; i < 4; ++i) {        // B: fp32 -> bf16
      int r = sr + i * 32;
      float4 vb = *(const float4*)(wq + (size_t)(n0 + r) * 512 + k0 + sc4);
      bf16x4 pb;
      pb[0]=(short)f2bf(vb.x); pb[1]=(short)f2bf(vb.y); pb[2]=(short)f2bf(vb.z); pb[3]=(short)f2bf(vb.w);
      *(bf16x4*)&s_b[r][sc4] = pb;
    }
    __syncthreads();
    bf16x8 af[4], bfr[4];
    #pragma unroll
    for (int mt = 0; mt < 4; ++mt) af[mt]  = *(const bf16x8*)&s_a[wr*64 + mt*16 + lm][quad*8];
    #pragma unroll
    for (int nt = 0; nt < 4; ++nt) bfr[nt] = *(const bf16x8*)&s_b[wc*64 + nt*16 + lm][quad*8];
    #pragma unroll
    for (int mt = 0; mt < 4; ++mt)
      #pragma unroll
      for (int nt = 0; nt < 4; ++nt)
        acc[mt][nt] = __builtin_amdgcn_mfma_f32_16x16x32_bf16(af[mt], bfr[nt], acc[mt][nt], 0, 0, 0);
  }
  #pragma unroll
  for (int nt = 0; nt < 4; ++nt) {
    int c = n0 + wc*64 + nt*16 + lm;
    float bias = bq[c];
    int sec = c >> 9, ch = c & 511, h = ch >> 6, d = ch & 63;
    #pragma unroll
    for (int mt = 0; mt < 4; ++mt) {
      #pragma unroll
      for (int r = 0; r < 4; ++r) {
        int grow = row0 + wr*64 + mt*16 + quad*4 + r;
        int b = grow >> 8, n = grow & 255;
        float val = acc[mt][nt][r] + bias;
        if (sec == 0)      q_ws[(((size_t)b*Hn + h)*Nn + n)*Dn + d] = f2bf(val * 0.125f);
        else if (sec == 1) k_ws[(((size_t)b*Hn + h)*Nn + n)*Dn + d] = f2bf(val);
        else               v_ws[(((size_t)b*Hn + h)*Dn + d)*Nn + n] = f2bf(val);
      }
    }
  }
}

// ---------------------------------------------------------------------------
// Kernel B: attention. Block = (b, 16-row q-tile); 4 waves x 2 heads.
// Bias-init and QK^T MFMA fused per key-tile so U-load temps die immediately
// (round-4 version split them -> 128 hoisted float4 loads -> VGPR cap + spill).
// ---------------------------------------------------------------------------
__global__ __launch_bounds__(256) void attn_kernel(
    const float* __restrict__ U, const float* __restrict__ w_u, const float* __restrict__ b_u,
    const unsigned short* __restrict__ q_ws, const unsigned short* __restrict__ k_ws,
    const unsigned short* __restrict__ v_ws, unsigned short* __restrict__ o_ws){
  __shared__ unsigned short s_p[4][16][264];   // per-wave P strip, +8 pad
  __shared__ float s_wu[64];
  __shared__ float s_bu[8];
  const int tid = threadIdx.x;
  const int wv = tid >> 6, lane = tid & 63;
  const int lm = lane & 15, quad = lane >> 4;
  const int blk = blockIdx.x;
  const int b = blk >> 4, qt0 = (blk & 15) * 16;
  if (tid < 64) s_wu[tid] = w_u[tid];
  if (tid < 8)  s_bu[tid] = b_u[tid];
  __syncthreads();   // only barrier in the kernel
  #pragma unroll 1
  for (int hh = 0; hh < 2; ++hh) {
    const int h = wv * 2 + hh;
    const size_t hb = (size_t)b * Hn + h;
    float wu[8];
    #pragma unroll
    for (int i = 0; i < 8; ++i) wu[i] = s_wu[h * 8 + i];
    const float bu = s_bu[h];
    const unsigned short* qrow = q_ws + (hb*Nn + qt0 + lm)*Dn;
    bf16x8 a0 = *(const bf16x8*)(qrow + quad*8);
    bf16x8 a1 = *(const bf16x8*)(qrow + 32 + quad*8);
    f32x4 acc[16];
    // --- fused: bias (U . w_u + b_u) as MFMA C-init, then QK^T accumulate
    #pragma unroll
    for (int kt = 0; kt < 16; ++kt) {
      f32x4 c;
      #pragma unroll
      for (int r = 0; r < 4; ++r) {
        const float4* up = (const float4*)(U +
            (((size_t)(b*Nn + qt0 + quad*4 + r))*Nn + kt*16 + lm)*8);
        float4 u0 = up[0], u1 = up[1];
        c[r] = bu + u0.x*wu[0] + u0.y*wu[1] + u0.z*wu[2] + u0.w*wu[3]
                  + u1.x*wu[4] + u1.y*wu[5] + u1.z*wu[6] + u1.w*wu[7];
      }
      const unsigned short* krow = k_ws + (hb*Nn + kt*16 + lm)*Dn;
      bf16x8 b0 = *(const bf16x8*)(krow + quad*8);
      bf16x8 b1 = *(const bf16x8*)(krow + 32 + quad*8);
      c = __builtin_amdgcn_mfma_f32_16x16x32_bf16(a0, b0, c, 0, 0, 0);
      c = __builtin_amdgcn_mfma_f32_16x16x32_bf16(a1, b1, c, 0, 0, 0);
      acc[kt] = c;
    }
    // --- softmax: row (quad*4+r) spans 16 kt in-lane x 16 lanes of this quad
    float mx[4], sm[4], inv[4];
    #pragma unroll
    for (int r = 0; r < 4; ++r) {
      float m = acc[0][r];
      #pragma unroll
      for (int kt = 1; kt < 16; ++kt) m = fmaxf(m, acc[kt][r]);
      #pragma unroll
      for (int msk = 1; msk < 16; msk <<= 1) m = fmaxf(m, __shfl_xor(m, msk));
      mx[r] = m; sm[r] = 0.f;
    }
    #pragma unroll
    for (int kt = 0; kt < 16; ++kt)
      #pragma unroll
      for (int r = 0; r < 4; ++r) {
        float e = __expf(acc[kt][r] - mx[r]);
        acc[kt][r] = e; sm[r] += e;
      }
    #pragma unroll
    for (int r = 0; r < 4; ++r) {
      float s = sm[r];
      #pragma unroll
      for (int msk = 1; msk < 16; msk <<= 1) s += __shfl_xor(s, msk);
      inv[r] = 1.0f / s;
    }
    // --- P (unnormalized, bf16) C-layout -> per-wave LDS strip
    #pragma unroll
    for (int kt = 0; kt < 16; ++kt)
      #pragma unroll
      for (int r = 0; r < 4; ++r)
        s_p[wv][quad*4 + r][kt*16 + lm] = f2bf(acc[kt][r]);
    // --- PV: A from s_p (A-layout), B from transposed V (global, L2-hot)
    f32x4 o[4] = {};
    #pragma unroll
    for (int ks = 0; ks < 8; ++ks) {
      bf16x8 ap = *(const bf16x8*)&s_p[wv][lm][ks*32 + quad*8];
      #pragma unroll
      for (int nt = 0; nt < 4; ++nt) {
        bf16x8 bv = *(const bf16x8*)(v_ws + (hb*Dn + nt*16 + lm)*Nn + ks*32 + quad*8);
        o[nt] = __builtin_amdgcn_mfma_f32_16x16x32_bf16(ap, bv, o[nt], 0, 0, 0);
      }
    }
    // --- normalize + store O -> o_ws[B,N,E]
    #pragma unroll
    for (int nt = 0; nt < 4; ++nt)
      #pragma unroll
      for (int r = 0; r < 4; ++r) {
        int n = qt0 + quad*4 + r;
        o_ws[((size_t)(b*Nn + n))*En + h*Dn + nt*16 + lm] = f2bf(o[nt][r] * inv[r]);
      }
  }
}

// ---------------------------------------------------------------------------
// Kernel C: out = o @ w_out^T + b_out (M=8192, N=512, K=512), fp32 out.
// ---------------------------------------------------------------------------
__global__ __launch_bounds__(256) void oproj_gemm(
    const unsigned short* __restrict__ o_ws, const float* __restrict__ wo,
    const float* __restrict__ bo, float* __restrict__ out){
  __shared__ unsigned short s_a[128][40];
  __shared__ unsigned short s_b[128][40];
  const int tid = threadIdx.x;
  const int bx = blockIdx.x;            // 0..3
  const int by = blockIdx.y;            // 0..63
  const int row0 = by * 128, n0 = bx * 128;
  const int lane = tid & 63, wv = tid >> 6;
  const int wr = wv >> 1, wc = wv & 1;
  const int lm = lane & 15, quad = lane >> 4;
  const int sr = tid >> 3, sc4 = (tid & 7) * 4;
  f32x4 acc[4][4] = {};
  for (int kc = 0; kc < 16; ++kc) {
    const int k0 = kc * 32;
    __syncthreads();
    #pragma unroll
    for (int i = 0; i < 2; ++i) {        // A: o_ws already bf16
      int g = tid * 2 + i;
      int r = g >> 2, c8 = (g & 3) * 8;
      *(bf16x8*)&s_a[r][c8] = *(const bf16x8*)(o_ws + (size_t)(row0 + r)*512 + k0 + c8);
    }
    #pragma unroll
    for (int i = 0; i < 4; ++i) {        // B: w_out fp32 -> bf16
      int r = sr + i * 32;
      float4 vb = *(const float4*)(wo + (size_t)(n0 + r) * 512 + k0 + sc4);
      bf16x4 pb;
      pb[0]=(short)f2bf(vb.x); pb[1]=(short)f2bf(vb.y); pb[2]=(short)f2bf(vb.z); pb[3]=(short)f2bf(vb.w);
      *(bf16x4*)&s_b[r][sc4] = pb;
    }
    __syncthreads();
    bf16x8 af[4], bfr[4];
    #pragma unroll
    for (int mt = 0; mt < 4; ++mt) af[mt]  = *(const bf16x8*)&s_a[wr*64 + mt*16 + lm][quad*8];
    #pragma unroll
    for (int nt = 0; nt < 4; ++nt) bfr[nt] = *(const bf16x8*)&s_b[wc*64 + nt*16 + lm][quad*8];
    #pragma unroll
    for (int mt = 0; mt < 4; ++mt)
      #pragma unroll
      for (int nt = 0; nt < 4; ++nt)
        acc[mt][nt] = __builtin_amdgcn_mfma_f32_16x16x32_bf16(af[mt], bfr[nt], acc[mt][nt], 0, 0, 0);
  }
  #pragma unroll
  for (int nt = 0; nt < 4; ++nt) {
    int c = n0 + wc*64 + nt*16 + lm;
    float bias = bo[c];
    #pragma unroll
    for (int mt = 0; mt < 4; ++mt)
      #pragma unroll
      for (int r = 0; r < 4; ++r) {
        int grow = row0 + wr*64 + mt*16 + quad*4 + r;
        out[(size_t)grow*512 + c] = acc[mt][nt][r] + bias;
      }
  }
}

extern "C" void kernel_launch(void* const* d_in, const int* in_sizes, int n_in,
                              void* d_out, int out_size, void* d_ws, size_t ws_size,
                              hipStream_t stream) {
  const float* x     = (const float*)d_in[0];
  const float* U     = (const float*)d_in[1];
  const float* w_qkv = (const float*)d_in[2];
  const float* b_qkv = (const float*)d_in[3];
  const float* w_out = (const float*)d_in[4];
  const float* b_out = (const float*)d_in[5];
  const float* w_u   = (const float*)d_in[6];
  const float* b_u   = (const float*)d_in[7];
  float* out = (float*)d_out;

  const size_t per = (size_t)Bn * Hn * Nn * Dn;       // 4,194,304 elements
  unsigned short* q_ws = (unsigned short*)d_ws;       // total ws: 32 MiB (proven fits)
  unsigned short* k_ws = q_ws + per;
  unsigned short* v_ws = k_ws + per;                  // transposed [B,H,D,N]
  unsigned short* o_ws = v_ws + per;                  // [B,N,E]; doubles as x_bf16 before attn

  convert_x <<<dim3(2048),  dim3(256), 0, stream>>>(x, o_ws);
  qkv_gemm  <<<dim3(12, 64), dim3(256), 0, stream>>>(o_ws, w_qkv, b_qkv, q_ws, k_ws, v_ws);
  attn_kernel<<<dim3(Bn * 16), dim3(256), 0, stream>>>(U, w_u, b_u, q_ws, k_ws, v_ws, o_ws);
  oproj_gemm<<<dim3(4, 64), dim3(256), 0, stream>>>(o_ws, w_out, b_out, out);
}

// Round 6
// 219.796 us; speedup vs baseline: 8.2743x; 1.5527x over previous
//
#include <hip/hip_runtime.h>
#include <stdint.h>

#define Bn 32
#define Nn 256
#define En 512
#define Hn 8
#define Dn 64

typedef __attribute__((ext_vector_type(8))) short bf16x8;   // MFMA A/B frag (4 VGPRs)
typedef __attribute__((ext_vector_type(4))) short bf16x4;
typedef __attribute__((ext_vector_type(4))) float f32x4;    // MFMA C/D frag

__device__ __forceinline__ unsigned short f2bf(float f){
  union{float f; uint32_t i;} v; v.f = f;
  uint32_t i = v.i;
  return (unsigned short)((i + 0x7fffu + ((i>>16)&1u)) >> 16);  // RNE
}

// ---------------------------------------------------------------------------
// Kernel 0: x fp32 -> bf16 into spare workspace (o_ws region, exactly x-sized).
// ---------------------------------------------------------------------------
__global__ __launch_bounds__(256) void convert_x(
    const float* __restrict__ x, unsigned short* __restrict__ xb){
  size_t i = ((size_t)blockIdx.x * 256 + threadIdx.x) * 8;
  float4 a = *(const float4*)(x + i);
  float4 b = *(const float4*)(x + i + 4);
  bf16x8 p;
  p[0]=(short)f2bf(a.x); p[1]=(short)f2bf(a.y); p[2]=(short)f2bf(a.z); p[3]=(short)f2bf(a.w);
  p[4]=(short)f2bf(b.x); p[5]=(short)f2bf(b.y); p[6]=(short)f2bf(b.z); p[7]=(short)f2bf(b.w);
  *(bf16x8*)(xb + i) = p;
}

// ---------------------------------------------------------------------------
// Kernel A: qkv = x @ w_qkv^T + b_qkv  (M=8192, N=1536, K=512), bf16 MFMA.
// q (pre-scaled by 1/8), k -> [B,H,N,D]; v -> transposed [B,H,D,N].
// ---------------------------------------------------------------------------
__global__ __launch_bounds__(256) void qkv_gemm(
    const unsigned short* __restrict__ xb, const float* __restrict__ wq,
    const float* __restrict__ bq,
    unsigned short* __restrict__ q_ws, unsigned short* __restrict__ k_ws,
    unsigned short* __restrict__ v_ws){
  __shared__ unsigned short s_a[128][40];   // +8 pad
  __shared__ unsigned short s_b[128][40];
  const int tid = threadIdx.x;
  const int bx = blockIdx.x;            // col tile 0..11
  const int by = blockIdx.y;            // row tile 0..63
  const int row0 = by * 128, n0 = bx * 128;
  const int lane = tid & 63, wv = tid >> 6;
  const int wr = wv >> 1, wc = wv & 1;
  const int lm = lane & 15, quad = lane >> 4;
  const int sr = tid >> 3, sc4 = (tid & 7) * 4;
  f32x4 acc[4][4] = {};
  for (int kc = 0; kc < 16; ++kc) {
    const int k0 = kc * 32;
    __syncthreads();
    #pragma unroll
    for (int i = 0; i < 2; ++i) {        // A: direct bf16 16B copies
      int g = tid * 2 + i;
      int r = g >> 2, c8 = (g & 3) * 8;
      *(bf16x8*)&s_a[r][c8] = *(const bf16x8*)(xb + (size_t)(row0 + r)*512 + k0 + c8);
    }
    #pragma unroll
    for (int i = 0; i < 4; ++i) {        // B: fp32 -> bf16
      int r = sr + i * 32;
      float4 vb = *(const float4*)(wq + (size_t)(n0 + r) * 512 + k0 + sc4);
      bf16x4 pb;
      pb[0]=(short)f2bf(vb.x); pb[1]=(short)f2bf(vb.y); pb[2]=(short)f2bf(vb.z); pb[3]=(short)f2bf(vb.w);
      *(bf16x4*)&s_b[r][sc4] = pb;
    }
    __syncthreads();
    bf16x8 af[4], bfr[4];
    #pragma unroll
    for (int mt = 0; mt < 4; ++mt) af[mt]  = *(const bf16x8*)&s_a[wr*64 + mt*16 + lm][quad*8];
    #pragma unroll
    for (int nt = 0; nt < 4; ++nt) bfr[nt] = *(const bf16x8*)&s_b[wc*64 + nt*16 + lm][quad*8];
    #pragma unroll
    for (int mt = 0; mt < 4; ++mt)
      #pragma unroll
      for (int nt = 0; nt < 4; ++nt)
        acc[mt][nt] = __builtin_amdgcn_mfma_f32_16x16x32_bf16(af[mt], bfr[nt], acc[mt][nt], 0, 0, 0);
  }
  #pragma unroll
  for (int nt = 0; nt < 4; ++nt) {
    int c = n0 + wc*64 + nt*16 + lm;
    float bias = bq[c];
    int sec = c >> 9, ch = c & 511, h = ch >> 6, d = ch & 63;
    #pragma unroll
    for (int mt = 0; mt < 4; ++mt) {
      #pragma unroll
      for (int r = 0; r < 4; ++r) {
        int grow = row0 + wr*64 + mt*16 + quad*4 + r;
        int b = grow >> 8, n = grow & 255;
        float val = acc[mt][nt][r] + bias;
        if (sec == 0)      q_ws[(((size_t)b*Hn + h)*Nn + n)*Dn + d] = f2bf(val * 0.125f);
        else if (sec == 1) k_ws[(((size_t)b*Hn + h)*Nn + n)*Dn + d] = f2bf(val);
        else               v_ws[(((size_t)b*Hn + h)*Dn + d)*Nn + n] = f2bf(val);
      }
    }
  }
}

// ---------------------------------------------------------------------------
// Kernel B: flash-style attention. Block = (b, 16-q-tile); wave wv owns heads
// {2wv, 2wv+1}. Keys processed in 32-wide chunks with online softmax (running
// m,l + rescaled O accumulator) -> no acc[16] register array, chunk loop is
// unroll-1 so the scheduler cannot hoist U loads (round-4/5 spill cause).
// Both heads of a wave share each U load. P transits a 10KB per-wave LDS
// strip (wave-internal, no barriers).
// ---------------------------------------------------------------------------
__global__ __launch_bounds__(256) void attn_kernel(
    const float* __restrict__ U, const float* __restrict__ w_u, const float* __restrict__ b_u,
    const unsigned short* __restrict__ q_ws, const unsigned short* __restrict__ k_ws,
    const unsigned short* __restrict__ v_ws, unsigned short* __restrict__ o_ws){
  __shared__ unsigned short s_p[4][2][16][40];   // [wave][head][row][32+8 pad]
  __shared__ float s_wu[64];
  __shared__ float s_bu[8];
  const int tid = threadIdx.x;
  const int wv = tid >> 6, lane = tid & 63;
  const int lm = lane & 15, quad = lane >> 4;
  const int blk = blockIdx.x;
  const int b = blk >> 4, qt0 = (blk & 15) * 16;
  if (tid < 64) s_wu[tid] = w_u[tid];
  if (tid < 8)  s_bu[tid] = b_u[tid];
  __syncthreads();   // only barrier in the kernel
  const int h0 = wv * 2, h1 = h0 + 1;
  const size_t hb0 = (size_t)b * Hn + h0, hb1 = hb0 + 1;
  float wu0[8], wu1[8];
  #pragma unroll
  for (int i = 0; i < 8; ++i) { wu0[i] = s_wu[h0*8 + i]; wu1[i] = s_wu[h1*8 + i]; }
  const float bu0 = s_bu[h0], bu1 = s_bu[h1];
  // Q fragments for both heads (q pre-scaled by 1/8 in qkv_gemm)
  const unsigned short* q0p = q_ws + (hb0*Nn + qt0 + lm)*Dn;
  const unsigned short* q1p = q_ws + (hb1*Nn + qt0 + lm)*Dn;
  const bf16x8 qa0 = *(const bf16x8*)(q0p + quad*8);
  const bf16x8 qa1 = *(const bf16x8*)(q0p + 32 + quad*8);
  const bf16x8 qb0 = *(const bf16x8*)(q1p + quad*8);
  const bf16x8 qb1 = *(const bf16x8*)(q1p + 32 + quad*8);
  f32x4 oa[4] = {}, ob[4] = {};
  float m0[4], m1[4], l0[4], l1[4];
  #pragma unroll
  for (int r = 0; r < 4; ++r) { m0[r] = m1[r] = -3.0e38f; l0[r] = l1[r] = 0.f; }
  const float* Ub = U + ((size_t)(b*Nn + qt0)) * Nn * 8;   // q-row stride 2048 floats
  #pragma unroll 1
  for (int ck = 0; ck < 8; ++ck) {
    f32x4 la0, la1, lb0, lb1;            // logits: head0 tiles 0/1, head1 tiles 0/1
    #pragma unroll
    for (int t = 0; t < 2; ++t) {
      const int key0 = ck*32 + t*16;
      f32x4 c0, c1;
      #pragma unroll
      for (int r = 0; r < 4; ++r) {
        const float4* up = (const float4*)(Ub + ((size_t)(quad*4+r)*Nn + key0 + lm)*8);
        float4 ua = up[0], uc = up[1];
        c0[r] = bu0 + ua.x*wu0[0] + ua.y*wu0[1] + ua.z*wu0[2] + ua.w*wu0[3]
                    + uc.x*wu0[4] + uc.y*wu0[5] + uc.z*wu0[6] + uc.w*wu0[7];
        c1[r] = bu1 + ua.x*wu1[0] + ua.y*wu1[1] + ua.z*wu1[2] + ua.w*wu1[3]
                    + uc.x*wu1[4] + uc.y*wu1[5] + uc.z*wu1[6] + uc.w*wu1[7];
      }
      const unsigned short* k0p = k_ws + (hb0*Nn + key0 + lm)*Dn;
      const unsigned short* k1p = k_ws + (hb1*Nn + key0 + lm)*Dn;
      bf16x8 kf;
      kf = *(const bf16x8*)(k0p + quad*8);
      c0 = __builtin_amdgcn_mfma_f32_16x16x32_bf16(qa0, kf, c0, 0, 0, 0);
      kf = *(const bf16x8*)(k0p + 32 + quad*8);
      c0 = __builtin_amdgcn_mfma_f32_16x16x32_bf16(qa1, kf, c0, 0, 0, 0);
      kf = *(const bf16x8*)(k1p + quad*8);
      c1 = __builtin_amdgcn_mfma_f32_16x16x32_bf16(qb0, kf, c1, 0, 0, 0);
      kf = *(const bf16x8*)(k1p + 32 + quad*8);
      c1 = __builtin_amdgcn_mfma_f32_16x16x32_bf16(qb1, kf, c1, 0, 0, 0);
      if (t == 0) { la0 = c0; lb0 = c1; } else { la1 = c0; lb1 = c1; }
    }
    // --- online softmax update per query row (quad*4+r); 16 lanes = 16 keys/tile
    #pragma unroll
    for (int r = 0; r < 4; ++r) {
      // head 0
      {
        float tm = fmaxf(la0[r], la1[r]);
        #pragma unroll
        for (int msk = 1; msk < 16; msk <<= 1) tm = fmaxf(tm, __shfl_xor(tm, msk));
        float mn = fmaxf(m0[r], tm);
        float al = __expf(m0[r] - mn);
        m0[r] = mn;
        float e0 = __expf(la0[r] - mn), e1 = __expf(la1[r] - mn);
        la0[r] = e0; la1[r] = e1;
        float s = e0 + e1;
        #pragma unroll
        for (int msk = 1; msk < 16; msk <<= 1) s += __shfl_xor(s, msk);
        l0[r] = l0[r] * al + s;
        #pragma unroll
        for (int nt = 0; nt < 4; ++nt) oa[nt][r] *= al;
      }
      // head 1
      {
        float tm = fmaxf(lb0[r], lb1[r]);
        #pragma unroll
        for (int msk = 1; msk < 16; msk <<= 1) tm = fmaxf(tm, __shfl_xor(tm, msk));
        float mn = fmaxf(m1[r], tm);
        float al = __expf(m1[r] - mn);
        m1[r] = mn;
        float e0 = __expf(lb0[r] - mn), e1 = __expf(lb1[r] - mn);
        lb0[r] = e0; lb1[r] = e1;
        float s = e0 + e1;
        #pragma unroll
        for (int msk = 1; msk < 16; msk <<= 1) s += __shfl_xor(s, msk);
        l1[r] = l1[r] * al + s;
        #pragma unroll
        for (int nt = 0; nt < 4; ++nt) ob[nt][r] *= al;
      }
    }
    // --- pack P (unnormalized, bf16) C-layout -> per-wave strip
    #pragma unroll
    for (int r = 0; r < 4; ++r) {
      s_p[wv][0][quad*4+r][lm]      = f2bf(la0[r]);
      s_p[wv][0][quad*4+r][16 + lm] = f2bf(la1[r]);
      s_p[wv][1][quad*4+r][lm]      = f2bf(lb0[r]);
      s_p[wv][1][quad*4+r][16 + lm] = f2bf(lb1[r]);
    }
    // --- PV for this 32-key chunk (A-layout read; wave-internal, no barrier)
    const bf16x8 ap0 = *(const bf16x8*)&s_p[wv][0][lm][quad*8];
    const bf16x8 ap1 = *(const bf16x8*)&s_p[wv][1][lm][quad*8];
    #pragma unroll
    for (int nt = 0; nt < 4; ++nt) {
      bf16x8 bv = *(const bf16x8*)(v_ws + (hb0*Dn + nt*16 + lm)*Nn + ck*32 + quad*8);
      oa[nt] = __builtin_amdgcn_mfma_f32_16x16x32_bf16(ap0, bv, oa[nt], 0, 0, 0);
      bv = *(const bf16x8*)(v_ws + (hb1*Dn + nt*16 + lm)*Nn + ck*32 + quad*8);
      ob[nt] = __builtin_amdgcn_mfma_f32_16x16x32_bf16(ap1, bv, ob[nt], 0, 0, 0);
    }
  }
  // --- finalize: normalize by l and store both heads
  #pragma unroll
  for (int r = 0; r < 4; ++r) {
    const float i0 = 1.0f / l0[r], i1 = 1.0f / l1[r];
    const int n = qt0 + quad*4 + r;
    #pragma unroll
    for (int nt = 0; nt < 4; ++nt) {
      o_ws[((size_t)(b*Nn + n))*En + h0*64 + nt*16 + lm] = f2bf(oa[nt][r] * i0);
      o_ws[((size_t)(b*Nn + n))*En + h1*64 + nt*16 + lm] = f2bf(ob[nt][r] * i1);
    }
  }
}

// ---------------------------------------------------------------------------
// Kernel C: out = o @ w_out^T + b_out (M=8192, N=512, K=512), fp32 out.
// ---------------------------------------------------------------------------
__global__ __launch_bounds__(256) void oproj_gemm(
    const unsigned short* __restrict__ o_ws, const float* __restrict__ wo,
    const float* __restrict__ bo, float* __restrict__ out){
  __shared__ unsigned short s_a[128][40];
  __shared__ unsigned short s_b[128][40];
  const int tid = threadIdx.x;
  const int bx = blockIdx.x;            // 0..3
  const int by = blockIdx.y;            // 0..63
  const int row0 = by * 128, n0 = bx * 128;
  const int lane = tid & 63, wv = tid >> 6;
  const int wr = wv >> 1, wc = wv & 1;
  const int lm = lane & 15, quad = lane >> 4;
  const int sr = tid >> 3, sc4 = (tid & 7) * 4;
  f32x4 acc[4][4] = {};
  for (int kc = 0; kc < 16; ++kc) {
    const int k0 = kc * 32;
    __syncthreads();
    #pragma unroll
    for (int i = 0; i < 2; ++i) {        // A: o_ws already bf16
      int g = tid * 2 + i;
      int r = g >> 2, c8 = (g & 3) * 8;
      *(bf16x8*)&s_a[r][c8] = *(const bf16x8*)(o_ws + (size_t)(row0 + r)*512 + k0 + c8);
    }
    #pragma unroll
    for (int i = 0; i < 4; ++i) {        // B: w_out fp32 -> bf16
      int r = sr + i * 32;
      float4 vb = *(const float4*)(wo + (size_t)(n0 + r) * 512 + k0 + sc4);
      bf16x4 pb;
      pb[0]=(short)f2bf(vb.x); pb[1]=(short)f2bf(vb.y); pb[2]=(short)f2bf(vb.z); pb[3]=(short)f2bf(vb.w);
      *(bf16x4*)&s_b[r][sc4] = pb;
    }
    __syncthreads();
    bf16x8 af[4], bfr[4];
    #pragma unroll
    for (int mt = 0; mt < 4; ++mt) af[mt]  = *(const bf16x8*)&s_a[wr*64 + mt*16 + lm][quad*8];
    #pragma unroll
    for (int nt = 0; nt < 4; ++nt) bfr[nt] = *(const bf16x8*)&s_b[wc*64 + nt*16 + lm][quad*8];
    #pragma unroll
    for (int mt = 0; mt < 4; ++mt)
      #pragma unroll
      for (int nt = 0; nt < 4; ++nt)
        acc[mt][nt] = __builtin_amdgcn_mfma_f32_16x16x32_bf16(af[mt], bfr[nt], acc[mt][nt], 0, 0, 0);
  }
  #pragma unroll
  for (int nt = 0; nt < 4; ++nt) {
    int c = n0 + wc*64 + nt*16 + lm;
    float bias = bo[c];
    #pragma unroll
    for (int mt = 0; mt < 4; ++mt)
      #pragma unroll
      for (int r = 0; r < 4; ++r) {
        int grow = row0 + wr*64 + mt*16 + quad*4 + r;
        out[(size_t)grow*512 + c] = acc[mt][nt][r] + bias;
      }
  }
}

extern "C" void kernel_launch(void* const* d_in, const int* in_sizes, int n_in,
                              void* d_out, int out_size, void* d_ws, size_t ws_size,
                              hipStream_t stream) {
  const float* x     = (const float*)d_in[0];
  const float* U     = (const float*)d_in[1];
  const float* w_qkv = (const float*)d_in[2];
  const float* b_qkv = (const float*)d_in[3];
  const float* w_out = (const float*)d_in[4];
  const float* b_out = (const float*)d_in[5];
  const float* w_u   = (const float*)d_in[6];
  const float* b_u   = (const float*)d_in[7];
  float* out = (float*)d_out;

  const size_t per = (size_t)Bn * Hn * Nn * Dn;       // 4,194,304 elements
  unsigned short* q_ws = (unsigned short*)d_ws;       // total ws: 32 MiB (proven fits)
  unsigned short* k_ws = q_ws + per;
  unsigned short* v_ws = k_ws + per;                  // transposed [B,H,D,N]
  unsigned short* o_ws = v_ws + per;                  // [B,N,E]; doubles as x_bf16 before attn

  convert_x <<<dim3(2048),  dim3(256), 0, stream>>>(x, o_ws);
  qkv_gemm  <<<dim3(12, 64), dim3(256), 0, stream>>>(o_ws, w_qkv, b_qkv, q_ws, k_ws, v_ws);
  attn_kernel<<<dim3(Bn * 16), dim3(256), 0, stream>>>(U, w_u, b_u, q_ws, k_ws, v_ws, o_ws);
  oproj_gemm<<<dim3(4, 64), dim3(256), 0, stream>>>(o_ws, w_out, b_out, out);
}